// Round 15
// baseline (74.155 us; speedup 1.0000x reference)
//
#include <hip/hip_runtime.h>
#include <hip/hip_bf16.h>
#include <math.h>

#define B_ 16
#define L_ 2048
#define H_ 1024
#define A_ 1024
#define C_ 5

#define NSPLIT 4                 // A-dim split across blocks in MFMA fallback
#define MT 32                    // rows per tile
#define KPH 256                  // K per staging phase (fallback GEMM)
#define TPB 16                   // tiles per batch
#define KC_BLOCKS (B_ * TPB * NSPLIT)   // 1024 MFMA fallback blocks (normally exit via cert)
#define KE_BLOCKS (B_ * L_ / 16)        // 2048 streaming blocks (16 rows each)
#define KW_BLOCKS 256                   // Wfrag conversion blocks
#define PB_BLOCKS 128                   // probe blocks (B_ * PBS)
#define PBS 8                           // probe slices per batch (128 a-cols each)
#define PROBE_THRESH 150.0f             // logit >= 150 -> m >= ~147 -> expf(-m) == 0.0f exactly

typedef __attribute__((ext_vector_type(8))) short short8v;
typedef __attribute__((ext_vector_type(4))) float float4v;

// ---- workspace layout (bytes) ----
static constexpr size_t OFF_SCAL   = 0;        // 2 f: denom, wsum
static constexpr size_t OFF_END    = 64;       // B ints
static constexpr size_t OFF_CNT    = 192;      // B ints
static constexpr size_t OFF_STARTS = 320;      // B*C ints
static constexpr size_t OFF_LIST   = 4096;                              // B*L ints
static constexpr size_t OFF_WF     = OFF_LIST + (size_t)B_ * L_ * 4;    // A*H bf16 (fragment-swizzled)
static constexpr size_t OFF_PP     = OFF_WF + (size_t)A_ * H_ * 2;      // NSPLIT*B*L f
static constexpr size_t OFF_D      = OFF_PP + (size_t)NSPLIT * B_ * L_ * 4;  // B*L f
static constexpr size_t OFF_PROBE  = OFF_D + (size_t)B_ * L_ * 4;       // B*PBS*16 f

static __device__ __forceinline__ unsigned short f2bf(float f) {
  unsigned u = __float_as_uint(f);
  unsigned r = (u >> 16) & 1u;
  return (unsigned short)((u + 0x7fffu + r) >> 16);
}

struct ProbeSmem {
  unsigned short Ws[128][72];   // 18.4 KB: W slice, one 64-K phase
  unsigned short Xs[16][72];    // 2.3 KB: 16 probe rows, one 64-K phase
  float red[4][16];
  int isum[4];
};
struct ScalSmem { float sf1[256]; float sf2[256]; };
union KWASmem {
  ProbeSmem probe;
  ScalSmem scal;
  int wsh[4];
};

// ============ kernel 1: kWA — stream ∥ probe ∥ masks ∥ scalars ∥ Wfrag ============
// bids [0, KE): streaming d[row]=dot(input row, Wcls) (raw inputs only)
// bids [KE, KE+128): SELF-SUFFICIENT probe: end-scan + own W conversion (raw inputs only)
// then B_ mask blocks, 1 scalar block, KW_BLOCKS Wfrag blocks (for the fallback path)
__global__ __launch_bounds__(256) void kWA(const int* __restrict__ attn,
                                           const int* __restrict__ mlm,
                                           const float* __restrict__ query,
                                           const float* __restrict__ Wcls,
                                           const float* __restrict__ Wh,
                                           const float* __restrict__ inp,
                                           const float* __restrict__ bh,
                                           float* __restrict__ ws_scal,
                                           int* __restrict__ endv,
                                           int* __restrict__ cnt,
                                           int* __restrict__ starts,
                                           int* __restrict__ list,
                                           unsigned short* __restrict__ Wfrag,
                                           float* __restrict__ d,
                                           float* __restrict__ probe) {
  __shared__ KWASmem smem;
  const int bid = blockIdx.x;
  const int t = threadIdx.x;
  const int w = t >> 6;
  const int lane = t & 63;

  if (bid < KE_BLOCKS) {
    // ---- streaming part: 4 rows per wave ----
    const int r0 = bid * 16 + w * 4;
    const int a0v = attn[r0], a1v = attn[r0 + 1], a2v = attn[r0 + 2], a3v = attn[r0 + 3];
    if ((a0v | a1v | a2v | a3v) == 0) return;
    float4 wv4[4];
#pragma unroll
    for (int k = 0; k < 4; ++k) wv4[k] = *(const float4*)(Wcls + k * 256 + lane * 4);
    const float* p0 = inp + (size_t)r0 * H_;
    float4 x0[4], x1[4], x2[4], x3[4];
    if (a0v) {
#pragma unroll
      for (int k = 0; k < 4; ++k) x0[k] = *(const float4*)(p0 + k * 256 + lane * 4);
    }
    if (a1v) {
#pragma unroll
      for (int k = 0; k < 4; ++k) x1[k] = *(const float4*)(p0 + H_ + k * 256 + lane * 4);
    }
    if (a2v) {
#pragma unroll
      for (int k = 0; k < 4; ++k) x2[k] = *(const float4*)(p0 + 2 * H_ + k * 256 + lane * 4);
    }
    if (a3v) {
#pragma unroll
      for (int k = 0; k < 4; ++k) x3[k] = *(const float4*)(p0 + 3 * H_ + k * 256 + lane * 4);
    }
#define DOTROW(XV, AV, IDX)                                                          \
    if (AV) {                                                                        \
      float acc = 0.f;                                                               \
      _Pragma("unroll")                                                              \
      for (int k = 0; k < 4; ++k)                                                    \
        acc += XV[k].x * wv4[k].x + XV[k].y * wv4[k].y +                             \
               XV[k].z * wv4[k].z + XV[k].w * wv4[k].w;                              \
      _Pragma("unroll")                                                              \
      for (int o = 1; o < 64; o <<= 1) acc += __shfl_xor(acc, o, 64);                \
      if (lane == 0) d[r0 + IDX] = acc;                                              \
    }
    DOTROW(x0, a0v, 0)
    DOTROW(x1, a1v, 1)
    DOTROW(x2, a2v, 2)
    DOTROW(x3, a3v, 3)
#undef DOTROW
    return;
  }

  const int g = bid - KE_BLOCKS;
  if (g < PB_BLOCKS) {
    // ---- probe: b = g>>3, slice sl = g&7 covers a-cols [sl*128, +128) ----
    const int b = g >> 3;
    const int sl = g & 7;
    const int* arow = attn + (size_t)b * L_;

    // end = sum(attn row); masked positions are [end, L) by construction
    int s_ = 0;
    for (int i = t; i < L_; i += 256) s_ += arow[i];
#pragma unroll
    for (int o = 1; o < 64; o <<= 1) s_ += __shfl_xor(s_, o, 64);
    if (lane == 0) smem.probe.isum[w] = s_;
    __syncthreads();
    const int end = smem.probe.isum[0] + smem.probe.isum[1] +
                    smem.probe.isum[2] + smem.probe.isum[3];

    const int lg = lane >> 4;
    const int lc = lane & 15;
    const int xrow = t >> 4;        // probe position index [0,16)
    const int xcb = (t & 15) * 4;   // X col base in phase
    const int pX = end + xrow;
    const int pl = (pX < L_) ? pX : (L_ - 1);
    const float* xsrc = inp + ((size_t)(b * L_ + pl)) * H_;
    const int wrow = t >> 1;        // W slice row [0,128)
    const int wcb = (t & 1) * 32;   // W col base in phase
    const float* wsrc = Wh + (size_t)(sl * 128 + wrow) * H_;

    float4v acc0 = (float4v){0.f, 0.f, 0.f, 0.f};
    float4v acc1 = (float4v){0.f, 0.f, 0.f, 0.f};

    for (int ph = 0; ph < 16; ++ph) {
      __syncthreads();  // previous phase's reads done
      {
        float4 u = *(const float4*)(xsrc + ph * 64 + xcb);
        unsigned short* dx = &smem.probe.Xs[xrow][xcb];
        dx[0] = f2bf(u.x); dx[1] = f2bf(u.y); dx[2] = f2bf(u.z); dx[3] = f2bf(u.w);
      }
#pragma unroll
      for (int j = 0; j < 4; ++j) {
        float4 u0 = *(const float4*)(wsrc + ph * 64 + wcb + j * 8);
        float4 u1 = *(const float4*)(wsrc + ph * 64 + wcb + j * 8 + 4);
        union { short8v v; unsigned short h[8]; } o;
        o.h[0] = f2bf(u0.x); o.h[1] = f2bf(u0.y); o.h[2] = f2bf(u0.z); o.h[3] = f2bf(u0.w);
        o.h[4] = f2bf(u1.x); o.h[5] = f2bf(u1.y); o.h[6] = f2bf(u1.z); o.h[7] = f2bf(u1.w);
        *(short8v*)&smem.probe.Ws[wrow][wcb + j * 8] = o.v;
      }
      __syncthreads();  // tiles ready
#pragma unroll
      for (int kk = 0; kk < 2; ++kk) {
        short8v av = *(const short8v*)&smem.probe.Xs[lc][kk * 32 + lg * 8];
        short8v bv0 = *(const short8v*)&smem.probe.Ws[w * 32 + lc][kk * 32 + lg * 8];
        short8v bv1 = *(const short8v*)&smem.probe.Ws[w * 32 + 16 + lc][kk * 32 + lg * 8];
        acc0 = __builtin_amdgcn_mfma_f32_16x16x32_bf16(av, bv0, acc0, 0, 0, 0);
        acc1 = __builtin_amdgcn_mfma_f32_16x16x32_bf16(av, bv1, acc1, 0, 0, 0);
      }
    }

    float pp[4] = {0.f, 0.f, 0.f, 0.f};
    {
      const int ag0 = sl * 128 + w * 32 + lc;
      const float q0 = query[ag0];
      const float b0 = bh[ag0];
      const int ag1 = ag0 + 16;
      const float q1 = query[ag1];
      const float b1 = bh[ag1];
#pragma unroll
      for (int r = 0; r < 4; ++r) {
        pp[r] = fmaf(tanhf(acc0[r] + b0), q0, pp[r]);
        pp[r] = fmaf(tanhf(acc1[r] + b1), q1, pp[r]);
      }
    }
#pragma unroll
    for (int r = 0; r < 4; ++r) {
#pragma unroll
      for (int o = 1; o < 16; o <<= 1)
        pp[r] += __shfl_xor(pp[r], o, 64);
    }
    __syncthreads();
    if (lc == 0) {
#pragma unroll
      for (int r = 0; r < 4; ++r) smem.probe.red[w][lg * 4 + r] = pp[r];
    }
    __syncthreads();
    if (t < 16) {
      const int p = end + t;
      const bool valid = (p < L_) && (arow[p] == 0);
      float s = smem.probe.red[0][t] + smem.probe.red[1][t] +
                smem.probe.red[2][t] + smem.probe.red[3][t];
      probe[((size_t)b * PBS + sl) * 16 + t] = valid ? s : 0.f;
    }
    return;
  }

  const int g2 = g - PB_BLOCKS;
  if (g2 < B_) {
    const int b = g2;
    const int* arow = attn + (size_t)b * L_;
    const int* mrow = mlm + (size_t)b * L_;
    const int base = t * 8;

    // ---- pass 1: attn==0 compaction (ascending) ----
    int loc[8];
    int lc2 = 0;
#pragma unroll
    for (int j = 0; j < 8; ++j) {
      int l = base + j;
      if (arow[l] == 0) loc[lc2++] = l;
    }
    int incl = lc2;
#pragma unroll
    for (int o = 1; o < 64; o <<= 1) {
      int v = __shfl_up(incl, o, 64);
      if (lane >= o) incl += v;
    }
    if (lane == 63) smem.wsh[w] = incl;
    __syncthreads();
    int pre = 0, total = 0;
#pragma unroll
    for (int i = 0; i < 4; ++i) {
      int s = smem.wsh[i];
      if (i < w) pre += s;
      total += s;
    }
    int excl = pre + incl - lc2;
    int* lrow = list + (size_t)b * L_;
    for (int j = 0; j < lc2; ++j) lrow[excl + j] = loc[j];
    if (t == 0) {
      cnt[b] = total;
      endv[b] = L_ - total;
    }
    __syncthreads();

    // ---- pass 2: mlm>0 markers ----
    int mloc[8];
    int mc = 0;
#pragma unroll
    for (int j = 0; j < 8; ++j) {
      int l = base + j;
      if (mrow[l] > 0) mloc[mc++] = l;
    }
    int incl2 = mc;
#pragma unroll
    for (int o = 1; o < 64; o <<= 1) {
      int v = __shfl_up(incl2, o, 64);
      if (lane >= o) incl2 += v;
    }
    if (lane == 63) smem.wsh[w] = incl2;
    __syncthreads();
    int pre2 = 0;
#pragma unroll
    for (int i = 0; i < 4; ++i) {
      if (i < w) pre2 += smem.wsh[i];
    }
    int excl2 = pre2 + incl2 - mc;
    for (int j = 0; j < mc; ++j) {
      int idx = excl2 + j;
      if (idx < C_) starts[b * C_ + idx] = mloc[j];
    }
  } else if (g2 == B_) {
    // ---- scalars ----
    float s = 0.f, s2 = 0.f;
    for (int i = t; i < A_; i += 256) {
      float q = query[i];
      s += q;
      s2 = fmaf(q, q, s2);
    }
    smem.scal.sf1[t] = s;
    smem.scal.sf2[t] = s2;
    __syncthreads();
    for (int off = 128; off >= 1; off >>= 1) {
      if (t < off) {
        smem.scal.sf1[t] += smem.scal.sf1[t + off];
        smem.scal.sf2[t] += smem.scal.sf2[t + off];
      }
      __syncthreads();
    }
    float qsum = smem.scal.sf1[0], qsq = smem.scal.sf2[0];
    __syncthreads();
    float wv = 0.f;
    for (int i = t; i < H_; i += 256) wv += Wcls[i];
    smem.scal.sf1[t] = wv;
    __syncthreads();
    for (int off = 128; off >= 1; off >>= 1) {
      if (t < off) smem.scal.sf1[t] += smem.scal.sf1[t + off];
      __syncthreads();
    }
    if (t == 0) {
      float var = (qsq - qsum * qsum / (float)A_) / (float)(A_ - 1);
      ws_scal[0] = sqrtf((float)A_ * var);
      ws_scal[1] = smem.scal.sf1[0];
    }
  } else {
    // ---- Wfrag conversion (for the fallback GEMM): block = (a_blk, kb-quarter) ----
    const int g4 = g2 - B_ - 1;          // [0, 256)
    const int ga = g4 >> 2;              // a_blk in [0,64)
    const int q = g4 & 3;                // kb quarter
    const int row = ga * 16 + (lane & 15);
    const int colb = (lane >> 4) * 8;
    const float* srcrow = Wh + (size_t)row * H_;
#pragma unroll
    for (int i = 0; i < 2; ++i) {
      const int kb = q * 8 + w * 2 + i;
      const float* src = srcrow + kb * 32 + colb;
      float4 u0 = *(const float4*)src;
      float4 u1 = *(const float4*)(src + 4);
      union { short8v v; unsigned short h[8]; } o;
      o.h[0] = f2bf(u0.x); o.h[1] = f2bf(u0.y); o.h[2] = f2bf(u0.z); o.h[3] = f2bf(u0.w);
      o.h[4] = f2bf(u1.x); o.h[5] = f2bf(u1.y); o.h[6] = f2bf(u1.z); o.h[7] = f2bf(u1.w);
      *(short8v*)(Wfrag + (((size_t)ga * 32 + kb) * 64 + lane) * 8) = o.v;
    }
  }
}

// ============ kernel 2: kMain — probe-gated MFMA GEMM fallback ============
__global__ __launch_bounds__(256, 4) void kMain(const float* __restrict__ inp,
                                                const unsigned short* __restrict__ Wfrag,
                                                const float* __restrict__ bh,
                                                const float* __restrict__ query,
                                                const int* __restrict__ cnt,
                                                const int* __restrict__ list,
                                                const float* __restrict__ ws_scal,
                                                const float* __restrict__ probe,
                                                float* __restrict__ probpart) {
  __shared__ __align__(16) unsigned short Xs[MT][KPH + 8];  // 32x264 bf16 = 16.9 KB
  __shared__ float red[4][MT];
  __shared__ int sskip;

  const int bid = blockIdx.x;
  const int t = threadIdx.x;
  const int w = t >> 6;
  const int lane = t & 63;

  const int as = (bid >> 3) & 3;
  const int T = (bid & 7) | ((bid >> 5) << 3);   // [0, 256)
  const int b = T >> 4;
  const int tile = T & 15;
  const int c0 = cnt[b];
  if (tile * MT >= c0) return;

  // probe certification
  if (t == 0) sskip = 0;
  __syncthreads();
  if (t < 16) {
    float s = 0.f;
#pragma unroll
    for (int p8 = 0; p8 < PBS; ++p8) s += probe[((size_t)b * PBS + p8) * 16 + t];
    float logit = -1000.0f * (s / ws_scal[0]);
    if (logit >= PROBE_THRESH) atomicOr(&sskip, 1);
  }
  __syncthreads();
  if (sskip) return;

  const int lg = lane >> 4;
  const int lc = lane & 15;

  const int srow = t >> 3;
  const int scol = (t & 7) * 32;
  const int gi = tile * MT + srow;
  const int gidx = (gi < c0) ? gi : (c0 - 1);
  const int xl = list[(size_t)b * L_ + gidx];
  const float* xptr = inp + ((size_t)(b * L_ + xl)) * H_ + scol;

  const unsigned short* wfbase = Wfrag + ((size_t)(as * 16 + w * 4) * 32) * 512 + lane * 8;

  float4v acc[2][4];
#pragma unroll
  for (int m = 0; m < 2; ++m)
#pragma unroll
    for (int n = 0; n < 4; ++n) acc[m][n] = (float4v){0.f, 0.f, 0.f, 0.f};

  for (int ph = 0; ph < H_ / KPH; ++ph) {
    __syncthreads();
#pragma unroll
    for (int j = 0; j < 4; ++j) {
      float4 u0 = *(const float4*)(xptr + ph * KPH + j * 8);
      float4 u1 = *(const float4*)(xptr + ph * KPH + j * 8 + 4);
      union { short8v v; unsigned short h[8]; } o;
      o.h[0] = f2bf(u0.x); o.h[1] = f2bf(u0.y); o.h[2] = f2bf(u0.z); o.h[3] = f2bf(u0.w);
      o.h[4] = f2bf(u1.x); o.h[5] = f2bf(u1.y); o.h[6] = f2bf(u1.z); o.h[7] = f2bf(u1.w);
      *(short8v*)&Xs[srow][scol + j * 8] = o.v;
    }
    __syncthreads();

    const unsigned short* fp0 = wfbase + (size_t)(ph * 8) * 512;
    short8v cb0 = *(const short8v*)(fp0);
    short8v cb1 = *(const short8v*)(fp0 + 32 * 512);
    short8v cb2 = *(const short8v*)(fp0 + 64 * 512);
    short8v cb3 = *(const short8v*)(fp0 + 96 * 512);
#pragma unroll
    for (int kk = 0; kk < 8; ++kk) {
      short8v nb0, nb1, nb2, nb3;
      if (kk < 7) {
        const unsigned short* fn = wfbase + (size_t)(ph * 8 + kk + 1) * 512;
        nb0 = *(const short8v*)(fn);
        nb1 = *(const short8v*)(fn + 32 * 512);
        nb2 = *(const short8v*)(fn + 64 * 512);
        nb3 = *(const short8v*)(fn + 96 * 512);
      }
      const int off = kk * 32 + lg * 8;
      short8v av0 = *(const short8v*)&Xs[lc][off];
      short8v av1 = *(const short8v*)&Xs[16 + lc][off];
      acc[0][0] = __builtin_amdgcn_mfma_f32_16x16x32_bf16(av0, cb0, acc[0][0], 0, 0, 0);
      acc[1][0] = __builtin_amdgcn_mfma_f32_16x16x32_bf16(av1, cb0, acc[1][0], 0, 0, 0);
      acc[0][1] = __builtin_amdgcn_mfma_f32_16x16x32_bf16(av0, cb1, acc[0][1], 0, 0, 0);
      acc[1][1] = __builtin_amdgcn_mfma_f32_16x16x32_bf16(av1, cb1, acc[1][1], 0, 0, 0);
      acc[0][2] = __builtin_amdgcn_mfma_f32_16x16x32_bf16(av0, cb2, acc[0][2], 0, 0, 0);
      acc[1][2] = __builtin_amdgcn_mfma_f32_16x16x32_bf16(av1, cb2, acc[1][2], 0, 0, 0);
      acc[0][3] = __builtin_amdgcn_mfma_f32_16x16x32_bf16(av0, cb3, acc[0][3], 0, 0, 0);
      acc[1][3] = __builtin_amdgcn_mfma_f32_16x16x32_bf16(av1, cb3, acc[1][3], 0, 0, 0);
      if (kk < 7) { cb0 = nb0; cb1 = nb1; cb2 = nb2; cb3 = nb3; }
    }
  }

  float pp[2][4];
#pragma unroll
  for (int m = 0; m < 2; ++m)
#pragma unroll
    for (int r = 0; r < 4; ++r) pp[m][r] = 0.f;

#pragma unroll
  for (int n = 0; n < 4; ++n) {
    const int ag = as * 256 + w * 64 + n * 16 + lc;
    const float q = query[ag];
    const float bb = bh[ag];
#pragma unroll
    for (int m = 0; m < 2; ++m)
#pragma unroll
      for (int r = 0; r < 4; ++r) {
        float v = acc[m][n][r] + bb;
        pp[m][r] = fmaf(tanhf(v), q, pp[m][r]);
      }
  }
#pragma unroll
  for (int m = 0; m < 2; ++m)
#pragma unroll
    for (int r = 0; r < 4; ++r) {
#pragma unroll
      for (int o = 1; o < 16; o <<= 1)
        pp[m][r] += __shfl_xor(pp[m][r], o, 64);
    }
  __syncthreads();
  if (lc == 0) {
#pragma unroll
    for (int m = 0; m < 2; ++m)
#pragma unroll
      for (int r = 0; r < 4; ++r)
        red[w][m * 16 + lg * 4 + r] = pp[m][r];
  }
  __syncthreads();
  if (t < MT) {
    const int i = tile * MT + t;
    if (i < c0) {
      float sv = red[0][t] + red[1][t] + red[2][t] + red[3][t];
      int l = list[(size_t)b * L_ + i];
      probpart[((size_t)as * B_ + b) * L_ + l] = sv;
    }
  }
}

// ============ kernel 3: kT — probe-gated softmax + segment sums + 80 outputs ============
__global__ __launch_bounds__(256) void kT(const int* __restrict__ cnt,
                                          const int* __restrict__ list,
                                          const float* __restrict__ probpart,
                                          const float* __restrict__ ws_scal,
                                          const float* __restrict__ d,
                                          const int* __restrict__ starts,
                                          const int* __restrict__ endv,
                                          const float* __restrict__ probe,
                                          const float* __restrict__ bcls,
                                          float* __restrict__ out) {
  __shared__ float lg[L_];
  __shared__ float red[256];
  __shared__ int sskip;
  const int b = blockIdx.x;
  const int t = threadIdx.x;
  const float denom = ws_scal[0];
  const int c0 = cnt[b];

  if (t == 0) sskip = 0;
  __syncthreads();
  if (t < 16) {
    float s = 0.f;
#pragma unroll
    for (int p8 = 0; p8 < PBS; ++p8) s += probe[((size_t)b * PBS + p8) * 16 + t];
    float logit = -1000.0f * (s / denom);
    if (logit >= PROBE_THRESH) atomicOr(&sskip, 1);
  }
  __syncthreads();
  const bool skip = (c0 > 0) && (sskip != 0);

  float att0 = 0.0f;
  if (!skip) {
    float mx = 0.0f;  // attended logits are exactly 0 and always exist
    for (int i = t; i < c0; i += 256) {
      int l = list[(size_t)b * L_ + i];
      float s = probpart[((size_t)0 * B_ + b) * L_ + l]
              + probpart[((size_t)1 * B_ + b) * L_ + l]
              + probpart[((size_t)2 * B_ + b) * L_ + l]
              + probpart[((size_t)3 * B_ + b) * L_ + l];
      float v = -1000.0f * (s / denom);
      lg[i] = v;
      mx = fmaxf(mx, v);
    }
    red[t] = mx;
    __syncthreads();
    for (int off = 128; off >= 1; off >>= 1) {
      if (t < off) red[t] = fmaxf(red[t], red[t + off]);
      __syncthreads();
    }
    const float m = red[0];
    __syncthreads();

    float zs = 0.f;
    for (int i = t; i < c0; i += 256) zs += expf(lg[i] - m);
    if (t == 0) zs += (float)(L_ - c0) * expf(-m);
    red[t] = zs;
    __syncthreads();
    for (int off = 128; off >= 1; off >>= 1) {
      if (t < off) red[t] += red[t + off];
      __syncthreads();
    }
    const float Z = red[0];
    __syncthreads();
    att0 = expf(-m) / Z;
  }

  for (int c = 0; c < C_; ++c) {
    const int st = starts[b * C_ + c];
    const int bound = (c < C_ - 1) ? (starts[b * C_ + c + 1] - 1) : (endv[b] - 1);
    const int lo = st + 1;
    const int hi = bound;
    float a = 0.f;
    for (int l = lo + t; l < hi; l += 256) a += d[(size_t)b * L_ + l];
    red[t] = a;
    __syncthreads();
    for (int off = 128; off >= 1; off >>= 1) {
      if (t < off) red[t] += red[t + off];
      __syncthreads();
    }
    if (t == 0) {
      int count = hi - lo;
      if (count < 0) count = 0;
      out[b * C_ + c] = red[0] + ws_scal[1] * att0 * (float)count + bcls[0];
    }
    __syncthreads();
  }
}

extern "C" void kernel_launch(void* const* d_in, const int* in_sizes, int n_in,
                              void* d_out, int out_size, void* d_ws, size_t ws_size,
                              hipStream_t stream) {
  const float* inp   = (const float*)d_in[0];
  const int*   attn  = (const int*)d_in[1];
  const int*   mlm   = (const int*)d_in[2];
  const float* Wh    = (const float*)d_in[3];
  const float* bh    = (const float*)d_in[4];
  const float* query = (const float*)d_in[5];
  const float* Wcls  = (const float*)d_in[6];
  const float* bcls  = (const float*)d_in[7];
  float* out = (float*)d_out;

  char* ws = (char*)d_ws;
  float*          ws_scal = (float*)(ws + OFF_SCAL);
  int*            endv    = (int*)(ws + OFF_END);
  int*            cnt     = (int*)(ws + OFF_CNT);
  int*            starts  = (int*)(ws + OFF_STARTS);
  int*            list    = (int*)(ws + OFF_LIST);
  unsigned short* Wfrag   = (unsigned short*)(ws + OFF_WF);
  float*          probpart= (float*)(ws + OFF_PP);
  float*          dvec    = (float*)(ws + OFF_D);
  float*          probe   = (float*)(ws + OFF_PROBE);

  hipLaunchKernelGGL(kWA, dim3(KE_BLOCKS + PB_BLOCKS + B_ + 1 + KW_BLOCKS), dim3(256), 0,
                     stream, attn, mlm, query, Wcls, Wh, inp, bh, ws_scal, endv, cnt,
                     starts, list, Wfrag, dvec, probe);
  hipLaunchKernelGGL(kMain, dim3(KC_BLOCKS), dim3(256), 0, stream,
                     inp, Wfrag, bh, query, cnt, list, ws_scal, probe, probpart);
  hipLaunchKernelGGL(kT, dim3(B_), dim3(256), 0, stream,
                     cnt, list, probpart, ws_scal, dvec, starts, endv, probe, bcls, out);
}

// Round 16
// 41.552 us; speedup vs baseline: 1.7846x; 1.7846x over previous
//
#include <hip/hip_runtime.h>
#include <hip/hip_bf16.h>
#include <math.h>

#define B_ 16
#define L_ 2048
#define H_ 1024
#define A_ 1024
#define C_ 5

#define NSPLIT 4                 // A-dim split across blocks in MFMA fallback
#define MT 32                    // rows per tile
#define KPH 256                  // K per staging phase (fallback GEMM + probe)
#define TPB 16                   // tiles per batch
#define KC_BLOCKS (B_ * TPB * NSPLIT)   // 1024 MFMA fallback blocks (normally exit via cert)
#define KE_BLOCKS (B_ * L_ / 16)        // 2048 streaming blocks (16 rows each)
#define KW_BLOCKS 256                   // Wfrag conversion blocks
#define PB_BLOCKS 128                   // probe blocks (B_ * PBS)
#define PBS 8                           // probe slices per batch (128 a-cols each)
#define PROBE_THRESH 150.0f             // logit >= 150 -> m >= ~147 -> expf(-m) == 0.0f exactly

typedef __attribute__((ext_vector_type(8))) short short8v;
typedef __attribute__((ext_vector_type(4))) float float4v;

// ---- workspace layout (bytes) ----
static constexpr size_t OFF_SCAL   = 0;        // 2 f: denom, wsum
static constexpr size_t OFF_END    = 64;       // B ints
static constexpr size_t OFF_CNT    = 192;      // B ints
static constexpr size_t OFF_STARTS = 320;      // B*C ints
static constexpr size_t OFF_LIST   = 4096;                              // B*L ints
static constexpr size_t OFF_WF     = OFF_LIST + (size_t)B_ * L_ * 4;    // A*H bf16 (fragment-swizzled)
static constexpr size_t OFF_PP     = OFF_WF + (size_t)A_ * H_ * 2;      // NSPLIT*B*L f
static constexpr size_t OFF_D      = OFF_PP + (size_t)NSPLIT * B_ * L_ * 4;  // B*L f
static constexpr size_t OFF_PROBE  = OFF_D + (size_t)B_ * L_ * 4;       // B*PBS*16 f

static __device__ __forceinline__ unsigned short f2bf(float f) {
  unsigned u = __float_as_uint(f);
  unsigned r = (u >> 16) & 1u;
  return (unsigned short)((u + 0x7fffu + r) >> 16);
}

// ============ kernel 1: kPrep — masks + scalars + Wfrag (small, fast) ============
// blocks [0,B): per-batch mask compaction; block B: scalars; [B+1, B+1+256): Wfrag.
__global__ __launch_bounds__(256) void kPrep(const int* __restrict__ attn,
                                             const int* __restrict__ mlm,
                                             const float* __restrict__ query,
                                             const float* __restrict__ Wcls,
                                             const float* __restrict__ Wh,
                                             float* __restrict__ ws_scal,
                                             int* __restrict__ endv,
                                             int* __restrict__ cnt,
                                             int* __restrict__ starts,
                                             int* __restrict__ list,
                                             unsigned short* __restrict__ Wfrag) {
  __shared__ int   wsh[4];
  __shared__ float sf1[256];
  __shared__ float sf2[256];
  const int bid = blockIdx.x;
  const int t = threadIdx.x;
  const int w = t >> 6;
  const int lane = t & 63;

  if (bid < B_) {
    const int b = bid;
    const int* arow = attn + (size_t)b * L_;
    const int* mrow = mlm + (size_t)b * L_;
    const int base = t * 8;

    // ---- pass 1: attn==0 compaction (ascending) ----
    int loc[8];
    int lc = 0;
#pragma unroll
    for (int j = 0; j < 8; ++j) {
      int l = base + j;
      if (arow[l] == 0) loc[lc++] = l;
    }
    int incl = lc;
#pragma unroll
    for (int o = 1; o < 64; o <<= 1) {
      int v = __shfl_up(incl, o, 64);
      if (lane >= o) incl += v;
    }
    if (lane == 63) wsh[w] = incl;
    __syncthreads();
    int pre = 0, total = 0;
#pragma unroll
    for (int i = 0; i < 4; ++i) {
      int s = wsh[i];
      if (i < w) pre += s;
      total += s;
    }
    int excl = pre + incl - lc;
    int* lrow = list + (size_t)b * L_;
    for (int j = 0; j < lc; ++j) lrow[excl + j] = loc[j];
    if (t == 0) {
      cnt[b] = total;
      endv[b] = L_ - total;
    }
    __syncthreads();

    // ---- pass 2: mlm>0 markers ----
    int mloc[8];
    int mc = 0;
#pragma unroll
    for (int j = 0; j < 8; ++j) {
      int l = base + j;
      if (mrow[l] > 0) mloc[mc++] = l;
    }
    int incl2 = mc;
#pragma unroll
    for (int o = 1; o < 64; o <<= 1) {
      int v = __shfl_up(incl2, o, 64);
      if (lane >= o) incl2 += v;
    }
    if (lane == 63) wsh[w] = incl2;
    __syncthreads();
    int pre2 = 0;
#pragma unroll
    for (int i = 0; i < 4; ++i) {
      if (i < w) pre2 += wsh[i];
    }
    int excl2 = pre2 + incl2 - mc;
    for (int j = 0; j < mc; ++j) {
      int idx = excl2 + j;
      if (idx < C_) starts[b * C_ + idx] = mloc[j];
    }
  } else if (bid == B_) {
    // ---- scalars ----
    float s = 0.f, s2 = 0.f;
    for (int i = t; i < A_; i += 256) {
      float q = query[i];
      s += q;
      s2 = fmaf(q, q, s2);
    }
    sf1[t] = s;
    sf2[t] = s2;
    __syncthreads();
    for (int off = 128; off >= 1; off >>= 1) {
      if (t < off) {
        sf1[t] += sf1[t + off];
        sf2[t] += sf2[t + off];
      }
      __syncthreads();
    }
    float qsum = sf1[0], qsq = sf2[0];
    __syncthreads();
    float wv = 0.f;
    for (int i = t; i < H_; i += 256) wv += Wcls[i];
    sf1[t] = wv;
    __syncthreads();
    for (int off = 128; off >= 1; off >>= 1) {
      if (t < off) sf1[t] += sf1[t + off];
      __syncthreads();
    }
    if (t == 0) {
      float var = (qsq - qsum * qsum / (float)A_) / (float)(A_ - 1);
      ws_scal[0] = sqrtf((float)A_ * var);
      ws_scal[1] = sf1[0];
    }
  } else {
    // ---- Wfrag conversion: block = (a_blk, kb-quarter) ----
    const int g4 = bid - B_ - 1;         // [0, 256)
    const int ga = g4 >> 2;              // a_blk in [0,64)
    const int q = g4 & 3;                // kb quarter
    const int row = ga * 16 + (lane & 15);
    const int colb = (lane >> 4) * 8;
    const float* srcrow = Wh + (size_t)row * H_;
#pragma unroll
    for (int i = 0; i < 2; ++i) {
      const int kb = q * 8 + w * 2 + i;
      const float* src = srcrow + kb * 32 + colb;
      float4 u0 = *(const float4*)src;
      float4 u1 = *(const float4*)(src + 4);
      union { short8v v; unsigned short h[8]; } o;
      o.h[0] = f2bf(u0.x); o.h[1] = f2bf(u0.y); o.h[2] = f2bf(u0.z); o.h[3] = f2bf(u0.w);
      o.h[4] = f2bf(u1.x); o.h[5] = f2bf(u1.y); o.h[6] = f2bf(u1.z); o.h[7] = f2bf(u1.w);
      *(short8v*)(Wfrag + (((size_t)ga * 32 + kb) * 64 + lane) * 8) = o.v;
    }
  }
}

// ============ kernel 2: kSP — probe (first) ∥ streaming W_cls dots ============
// bids [0, PB_BLOCKS): probe b=bid>>3, slice sl=bid&7 (reads Wfrag/list from kPrep;
//   L2-bound, hides under the HBM-bound stream).
// bids [PB_BLOCKS, +KE_BLOCKS): streaming, 4 rows/wave, d[row]=dot(row,Wcls).
__global__ __launch_bounds__(256) void kSP(const float* __restrict__ inp,
                                           const unsigned short* __restrict__ Wfrag,
                                           const float* __restrict__ bh,
                                           const float* __restrict__ query,
                                           const float* __restrict__ Wcls,
                                           const int* __restrict__ attn,
                                           const int* __restrict__ cnt,
                                           const int* __restrict__ list,
                                           float* __restrict__ probe,
                                           float* __restrict__ d) {
  __shared__ __align__(16) unsigned short Xs[16][KPH + 8];  // 8.4 KB
  __shared__ float red[4][16];
  const int bid = blockIdx.x;
  const int t = threadIdx.x;
  const int w = t >> 6;
  const int lane = t & 63;

  if (bid >= PB_BLOCKS) {
    // ---- streaming part: 4 rows per wave ----
    const int r0 = (bid - PB_BLOCKS) * 16 + w * 4;
    const int a0v = attn[r0], a1v = attn[r0 + 1], a2v = attn[r0 + 2], a3v = attn[r0 + 3];
    if ((a0v | a1v | a2v | a3v) == 0) return;
    float4 wv4[4];
#pragma unroll
    for (int k = 0; k < 4; ++k) wv4[k] = *(const float4*)(Wcls + k * 256 + lane * 4);
    const float* p0 = inp + (size_t)r0 * H_;
    float4 x0[4], x1[4], x2[4], x3[4];
    if (a0v) {
#pragma unroll
      for (int k = 0; k < 4; ++k) x0[k] = *(const float4*)(p0 + k * 256 + lane * 4);
    }
    if (a1v) {
#pragma unroll
      for (int k = 0; k < 4; ++k) x1[k] = *(const float4*)(p0 + H_ + k * 256 + lane * 4);
    }
    if (a2v) {
#pragma unroll
      for (int k = 0; k < 4; ++k) x2[k] = *(const float4*)(p0 + 2 * H_ + k * 256 + lane * 4);
    }
    if (a3v) {
#pragma unroll
      for (int k = 0; k < 4; ++k) x3[k] = *(const float4*)(p0 + 3 * H_ + k * 256 + lane * 4);
    }
#define DOTROW(XV, AV, IDX)                                                          \
    if (AV) {                                                                        \
      float acc = 0.f;                                                               \
      _Pragma("unroll")                                                              \
      for (int k = 0; k < 4; ++k)                                                    \
        acc += XV[k].x * wv4[k].x + XV[k].y * wv4[k].y +                             \
               XV[k].z * wv4[k].z + XV[k].w * wv4[k].w;                              \
      _Pragma("unroll")                                                              \
      for (int o = 1; o < 64; o <<= 1) acc += __shfl_xor(acc, o, 64);                \
      if (lane == 0) d[r0 + IDX] = acc;                                              \
    }
    DOTROW(x0, a0v, 0)
    DOTROW(x1, a1v, 1)
    DOTROW(x2, a2v, 2)
    DOTROW(x3, a3v, 3)
#undef DOTROW
    return;
  }

  // ---- probe part (round-14 shape: coalesced Wfrag reads) ----
  const int b = bid >> 3;
  const int sl = bid & 7;
  const int c0 = cnt[b];
  const int lg = lane >> 4;
  const int lc = lane & 15;

  const int srow = t >> 4;
  const int scol = (t & 15) * 16;
  int pi = srow;
  if (pi >= c0) pi = (c0 > 0) ? (c0 - 1) : 0;
  const int xl = (c0 > 0) ? list[(size_t)b * L_ + pi] : 0;
  const float* xptr = inp + ((size_t)(b * L_ + xl)) * H_ + scol;

  const unsigned short* wf = Wfrag + ((size_t)(sl * 8 + w * 2) * 32) * 512 + lane * 8;

  float4v acc0 = (float4v){0.f, 0.f, 0.f, 0.f};
  float4v acc1 = (float4v){0.f, 0.f, 0.f, 0.f};

  for (int ph = 0; ph < H_ / KPH; ++ph) {
    __syncthreads();
#pragma unroll
    for (int j = 0; j < 2; ++j) {
      float4 u0 = *(const float4*)(xptr + ph * KPH + j * 8);
      float4 u1 = *(const float4*)(xptr + ph * KPH + j * 8 + 4);
      union { short8v v; unsigned short h[8]; } o;
      o.h[0] = f2bf(u0.x); o.h[1] = f2bf(u0.y); o.h[2] = f2bf(u0.z); o.h[3] = f2bf(u0.w);
      o.h[4] = f2bf(u1.x); o.h[5] = f2bf(u1.y); o.h[6] = f2bf(u1.z); o.h[7] = f2bf(u1.w);
      *(short8v*)&Xs[srow][scol + j * 8] = o.v;
    }
    __syncthreads();
#pragma unroll
    for (int kk = 0; kk < 8; ++kk) {
      const int kb = ph * 8 + kk;
      short8v bv0 = *(const short8v*)(wf + (size_t)kb * 512);
      short8v bv1 = *(const short8v*)(wf + (size_t)kb * 512 + 32 * 512);
      short8v av = *(const short8v*)&Xs[lc][kk * 32 + lg * 8];
      acc0 = __builtin_amdgcn_mfma_f32_16x16x32_bf16(av, bv0, acc0, 0, 0, 0);
      acc1 = __builtin_amdgcn_mfma_f32_16x16x32_bf16(av, bv1, acc1, 0, 0, 0);
    }
  }

  float pp[4] = {0.f, 0.f, 0.f, 0.f};
  {
    const int ag0 = sl * 128 + w * 32 + lc;
    const float q0 = query[ag0];
    const float b0 = bh[ag0];
    const int ag1 = ag0 + 16;
    const float q1 = query[ag1];
    const float b1 = bh[ag1];
#pragma unroll
    for (int r = 0; r < 4; ++r) {
      pp[r] = fmaf(tanhf(acc0[r] + b0), q0, pp[r]);
      pp[r] = fmaf(tanhf(acc1[r] + b1), q1, pp[r]);
    }
  }
#pragma unroll
  for (int r = 0; r < 4; ++r) {
#pragma unroll
    for (int o = 1; o < 16; o <<= 1)
      pp[r] += __shfl_xor(pp[r], o, 64);
  }
  __syncthreads();
  if (lc == 0) {
#pragma unroll
    for (int r = 0; r < 4; ++r) red[w][lg * 4 + r] = pp[r];
  }
  __syncthreads();
  if (t < 16) {
    float s = red[0][t] + red[1][t] + red[2][t] + red[3][t];
    probe[((size_t)b * PBS + sl) * 16 + t] = (c0 > 0) ? s : 0.f;
  }
}

// ============ kernel 3: kMain — probe-gated MFMA GEMM fallback ============
__global__ __launch_bounds__(256, 4) void kMain(const float* __restrict__ inp,
                                                const unsigned short* __restrict__ Wfrag,
                                                const float* __restrict__ bh,
                                                const float* __restrict__ query,
                                                const int* __restrict__ cnt,
                                                const int* __restrict__ list,
                                                const float* __restrict__ ws_scal,
                                                const float* __restrict__ probe,
                                                float* __restrict__ probpart) {
  __shared__ __align__(16) unsigned short Xs[MT][KPH + 8];  // 16.9 KB
  __shared__ float red[4][MT];
  __shared__ int sskip;

  const int bid = blockIdx.x;
  const int t = threadIdx.x;
  const int w = t >> 6;
  const int lane = t & 63;

  const int as = (bid >> 3) & 3;
  const int T = (bid & 7) | ((bid >> 5) << 3);   // [0, 256)
  const int b = T >> 4;
  const int tile = T & 15;
  const int c0 = cnt[b];
  if (tile * MT >= c0) return;

  if (t == 0) sskip = 0;
  __syncthreads();
  if (t < 16) {
    float s = 0.f;
#pragma unroll
    for (int p8 = 0; p8 < PBS; ++p8) s += probe[((size_t)b * PBS + p8) * 16 + t];
    float logit = -1000.0f * (s / ws_scal[0]);
    if (logit >= PROBE_THRESH) atomicOr(&sskip, 1);
  }
  __syncthreads();
  if (sskip) return;

  const int lg = lane >> 4;
  const int lc = lane & 15;

  const int srow = t >> 3;
  const int scol = (t & 7) * 32;
  const int gi = tile * MT + srow;
  const int gidx = (gi < c0) ? gi : (c0 - 1);
  const int xl = list[(size_t)b * L_ + gidx];
  const float* xptr = inp + ((size_t)(b * L_ + xl)) * H_ + scol;

  const unsigned short* wfbase = Wfrag + ((size_t)(as * 16 + w * 4) * 32) * 512 + lane * 8;

  float4v acc[2][4];
#pragma unroll
  for (int m = 0; m < 2; ++m)
#pragma unroll
    for (int n = 0; n < 4; ++n) acc[m][n] = (float4v){0.f, 0.f, 0.f, 0.f};

  for (int ph = 0; ph < H_ / KPH; ++ph) {
    __syncthreads();
#pragma unroll
    for (int j = 0; j < 4; ++j) {
      float4 u0 = *(const float4*)(xptr + ph * KPH + j * 8);
      float4 u1 = *(const float4*)(xptr + ph * KPH + j * 8 + 4);
      union { short8v v; unsigned short h[8]; } o;
      o.h[0] = f2bf(u0.x); o.h[1] = f2bf(u0.y); o.h[2] = f2bf(u0.z); o.h[3] = f2bf(u0.w);
      o.h[4] = f2bf(u1.x); o.h[5] = f2bf(u1.y); o.h[6] = f2bf(u1.z); o.h[7] = f2bf(u1.w);
      *(short8v*)&Xs[srow][scol + j * 8] = o.v;
    }
    __syncthreads();

    const unsigned short* fp0 = wfbase + (size_t)(ph * 8) * 512;
    short8v cb0 = *(const short8v*)(fp0);
    short8v cb1 = *(const short8v*)(fp0 + 32 * 512);
    short8v cb2 = *(const short8v*)(fp0 + 64 * 512);
    short8v cb3 = *(const short8v*)(fp0 + 96 * 512);
#pragma unroll
    for (int kk = 0; kk < 8; ++kk) {
      short8v nb0, nb1, nb2, nb3;
      if (kk < 7) {
        const unsigned short* fn = wfbase + (size_t)(ph * 8 + kk + 1) * 512;
        nb0 = *(const short8v*)(fn);
        nb1 = *(const short8v*)(fn + 32 * 512);
        nb2 = *(const short8v*)(fn + 64 * 512);
        nb3 = *(const short8v*)(fn + 96 * 512);
      }
      const int off = kk * 32 + lg * 8;
      short8v av0 = *(const short8v*)&Xs[lc][off];
      short8v av1 = *(const short8v*)&Xs[16 + lc][off];
      acc[0][0] = __builtin_amdgcn_mfma_f32_16x16x32_bf16(av0, cb0, acc[0][0], 0, 0, 0);
      acc[1][0] = __builtin_amdgcn_mfma_f32_16x16x32_bf16(av1, cb0, acc[1][0], 0, 0, 0);
      acc[0][1] = __builtin_amdgcn_mfma_f32_16x16x32_bf16(av0, cb1, acc[0][1], 0, 0, 0);
      acc[1][1] = __builtin_amdgcn_mfma_f32_16x16x32_bf16(av1, cb1, acc[1][1], 0, 0, 0);
      acc[0][2] = __builtin_amdgcn_mfma_f32_16x16x32_bf16(av0, cb2, acc[0][2], 0, 0, 0);
      acc[1][2] = __builtin_amdgcn_mfma_f32_16x16x32_bf16(av1, cb2, acc[1][2], 0, 0, 0);
      acc[0][3] = __builtin_amdgcn_mfma_f32_16x16x32_bf16(av0, cb3, acc[0][3], 0, 0, 0);
      acc[1][3] = __builtin_amdgcn_mfma_f32_16x16x32_bf16(av1, cb3, acc[1][3], 0, 0, 0);
      if (kk < 7) { cb0 = nb0; cb1 = nb1; cb2 = nb2; cb3 = nb3; }
    }
  }

  float pp[2][4];
#pragma unroll
  for (int m = 0; m < 2; ++m)
#pragma unroll
    for (int r = 0; r < 4; ++r) pp[m][r] = 0.f;

#pragma unroll
  for (int n = 0; n < 4; ++n) {
    const int ag = as * 256 + w * 64 + n * 16 + lc;
    const float q = query[ag];
    const float bb = bh[ag];
#pragma unroll
    for (int m = 0; m < 2; ++m)
#pragma unroll
      for (int r = 0; r < 4; ++r) {
        float v = acc[m][n][r] + bb;
        pp[m][r] = fmaf(tanhf(v), q, pp[m][r]);
      }
  }
#pragma unroll
  for (int m = 0; m < 2; ++m)
#pragma unroll
    for (int r = 0; r < 4; ++r) {
#pragma unroll
      for (int o = 1; o < 16; o <<= 1)
        pp[m][r] += __shfl_xor(pp[m][r], o, 64);
    }
  __syncthreads();
  if (lc == 0) {
#pragma unroll
    for (int m = 0; m < 2; ++m)
#pragma unroll
      for (int r = 0; r < 4; ++r)
        red[w][m * 16 + lg * 4 + r] = pp[m][r];
  }
  __syncthreads();
  if (t < MT) {
    const int i = tile * MT + t;
    if (i < c0) {
      float sv = red[0][t] + red[1][t] + red[2][t] + red[3][t];
      int l = list[(size_t)b * L_ + i];
      probpart[((size_t)as * B_ + b) * L_ + l] = sv;
    }
  }
}

// ============ kernel 4: kT — probe-gated softmax + segment sums + 80 outputs ============
__global__ __launch_bounds__(256) void kT(const int* __restrict__ cnt,
                                          const int* __restrict__ list,
                                          const float* __restrict__ probpart,
                                          const float* __restrict__ ws_scal,
                                          const float* __restrict__ d,
                                          const int* __restrict__ starts,
                                          const int* __restrict__ endv,
                                          const float* __restrict__ probe,
                                          const float* __restrict__ bcls,
                                          float* __restrict__ out) {
  __shared__ float lg[L_];
  __shared__ float red[256];
  __shared__ int sskip;
  const int b = blockIdx.x;
  const int t = threadIdx.x;
  const float denom = ws_scal[0];
  const int c0 = cnt[b];

  if (t == 0) sskip = 0;
  __syncthreads();
  if (t < 16) {
    float s = 0.f;
#pragma unroll
    for (int p8 = 0; p8 < PBS; ++p8) s += probe[((size_t)b * PBS + p8) * 16 + t];
    float logit = -1000.0f * (s / denom);
    if (logit >= PROBE_THRESH) atomicOr(&sskip, 1);
  }
  __syncthreads();
  const bool skip = (c0 > 0) && (sskip != 0);

  float att0 = 0.0f;
  if (!skip) {
    float mx = 0.0f;  // attended logits are exactly 0 and always exist
    for (int i = t; i < c0; i += 256) {
      int l = list[(size_t)b * L_ + i];
      float s = probpart[((size_t)0 * B_ + b) * L_ + l]
              + probpart[((size_t)1 * B_ + b) * L_ + l]
              + probpart[((size_t)2 * B_ + b) * L_ + l]
              + probpart[((size_t)3 * B_ + b) * L_ + l];
      float v = -1000.0f * (s / denom);
      lg[i] = v;
      mx = fmaxf(mx, v);
    }
    red[t] = mx;
    __syncthreads();
    for (int off = 128; off >= 1; off >>= 1) {
      if (t < off) red[t] = fmaxf(red[t], red[t + off]);
      __syncthreads();
    }
    const float m = red[0];
    __syncthreads();

    float zs = 0.f;
    for (int i = t; i < c0; i += 256) zs += expf(lg[i] - m);
    if (t == 0) zs += (float)(L_ - c0) * expf(-m);
    red[t] = zs;
    __syncthreads();
    for (int off = 128; off >= 1; off >>= 1) {
      if (t < off) red[t] += red[t + off];
      __syncthreads();
    }
    const float Z = red[0];
    __syncthreads();
    att0 = expf(-m) / Z;
  }

  for (int c = 0; c < C_; ++c) {
    const int st = starts[b * C_ + c];
    const int bound = (c < C_ - 1) ? (starts[b * C_ + c + 1] - 1) : (endv[b] - 1);
    const int lo = st + 1;
    const int hi = bound;
    float a = 0.f;
    for (int l = lo + t; l < hi; l += 256) a += d[(size_t)b * L_ + l];
    red[t] = a;
    __syncthreads();
    for (int off = 128; off >= 1; off >>= 1) {
      if (t < off) red[t] += red[t + off];
      __syncthreads();
    }
    if (t == 0) {
      int count = hi - lo;
      if (count < 0) count = 0;
      out[b * C_ + c] = red[0] + ws_scal[1] * att0 * (float)count + bcls[0];
    }
    __syncthreads();
  }
}

extern "C" void kernel_launch(void* const* d_in, const int* in_sizes, int n_in,
                              void* d_out, int out_size, void* d_ws, size_t ws_size,
                              hipStream_t stream) {
  const float* inp   = (const float*)d_in[0];
  const int*   attn  = (const int*)d_in[1];
  const int*   mlm   = (const int*)d_in[2];
  const float* Wh    = (const float*)d_in[3];
  const float* bh    = (const float*)d_in[4];
  const float* query = (const float*)d_in[5];
  const float* Wcls  = (const float*)d_in[6];
  const float* bcls  = (const float*)d_in[7];
  float* out = (float*)d_out;

  char* ws = (char*)d_ws;
  float*          ws_scal = (float*)(ws + OFF_SCAL);
  int*            endv    = (int*)(ws + OFF_END);
  int*            cnt     = (int*)(ws + OFF_CNT);
  int*            starts  = (int*)(ws + OFF_STARTS);
  int*            list    = (int*)(ws + OFF_LIST);
  unsigned short* Wfrag   = (unsigned short*)(ws + OFF_WF);
  float*          probpart= (float*)(ws + OFF_PP);
  float*          dvec    = (float*)(ws + OFF_D);
  float*          probe   = (float*)(ws + OFF_PROBE);

  hipLaunchKernelGGL(kPrep, dim3(B_ + 1 + KW_BLOCKS), dim3(256), 0, stream,
                     attn, mlm, query, Wcls, Wh, ws_scal, endv, cnt, starts, list, Wfrag);
  hipLaunchKernelGGL(kSP, dim3(PB_BLOCKS + KE_BLOCKS), dim3(256), 0, stream,
                     inp, Wfrag, bh, query, Wcls, attn, cnt, list, probe, dvec);
  hipLaunchKernelGGL(kMain, dim3(KC_BLOCKS), dim3(256), 0, stream,
                     inp, Wfrag, bh, query, cnt, list, ws_scal, probe, probpart);
  hipLaunchKernelGGL(kT, dim3(B_), dim3(256), 0, stream,
                     cnt, list, probpart, ws_scal, dvec, starts, endv, probe, bcls, out);
}

// Round 17
// 39.677 us; speedup vs baseline: 1.8690x; 1.0472x over previous
//
#include <hip/hip_runtime.h>
#include <hip/hip_bf16.h>
#include <math.h>

#define B_ 16
#define L_ 2048
#define H_ 1024
#define A_ 1024
#define C_ 5

#define KPH 256                  // K per staging phase (probe / fallback)
#define KE_BLOCKS (B_ * L_ / 16)        // 2048 streaming blocks (16 rows each)
#define KW_BLOCKS 256                   // Wfrag conversion blocks
#define PB_BLOCKS 128                   // probe blocks (B_ * PBS)
#define PBS 8                           // probe slices per batch (128 a-cols each)
#define PROBE_THRESH 150.0f             // logit >= 150 -> m >= ~147 -> expf(-m) == 0.0f exactly

typedef __attribute__((ext_vector_type(8))) short short8v;
typedef __attribute__((ext_vector_type(4))) float float4v;

// ---- workspace layout (bytes) ----
static constexpr size_t OFF_SCAL   = 0;        // 2 f: denom, wsum
static constexpr size_t OFF_END    = 64;       // B ints
static constexpr size_t OFF_CNT    = 192;      // B ints
static constexpr size_t OFF_STARTS = 320;      // B*C ints
static constexpr size_t OFF_LIST   = 4096;                              // B*L ints
static constexpr size_t OFF_WF     = OFF_LIST + (size_t)B_ * L_ * 4;    // A*H bf16 (fragment-swizzled)
static constexpr size_t OFF_D      = OFF_WF + (size_t)A_ * H_ * 2;      // B*L f
static constexpr size_t OFF_PROBE  = OFF_D + (size_t)B_ * L_ * 4;       // B*PBS*16 f

static __device__ __forceinline__ unsigned short f2bf(float f) {
  unsigned u = __float_as_uint(f);
  unsigned r = (u >> 16) & 1u;
  return (unsigned short)((u + 0x7fffu + r) >> 16);
}

// ============ kernel 1: kPrep — masks + scalars + Wfrag (small, fast) ============
__global__ __launch_bounds__(256) void kPrep(const int* __restrict__ attn,
                                             const int* __restrict__ mlm,
                                             const float* __restrict__ query,
                                             const float* __restrict__ Wcls,
                                             const float* __restrict__ Wh,
                                             float* __restrict__ ws_scal,
                                             int* __restrict__ endv,
                                             int* __restrict__ cnt,
                                             int* __restrict__ starts,
                                             int* __restrict__ list,
                                             unsigned short* __restrict__ Wfrag) {
  __shared__ int   wsh[4];
  __shared__ float sf1[256];
  __shared__ float sf2[256];
  const int bid = blockIdx.x;
  const int t = threadIdx.x;
  const int w = t >> 6;
  const int lane = t & 63;

  if (bid < B_) {
    const int b = bid;
    const int* arow = attn + (size_t)b * L_;
    const int* mrow = mlm + (size_t)b * L_;
    const int base = t * 8;

    // ---- pass 1: attn==0 compaction (ascending) ----
    int loc[8];
    int lc = 0;
#pragma unroll
    for (int j = 0; j < 8; ++j) {
      int l = base + j;
      if (arow[l] == 0) loc[lc++] = l;
    }
    int incl = lc;
#pragma unroll
    for (int o = 1; o < 64; o <<= 1) {
      int v = __shfl_up(incl, o, 64);
      if (lane >= o) incl += v;
    }
    if (lane == 63) wsh[w] = incl;
    __syncthreads();
    int pre = 0, total = 0;
#pragma unroll
    for (int i = 0; i < 4; ++i) {
      int s = wsh[i];
      if (i < w) pre += s;
      total += s;
    }
    int excl = pre + incl - lc;
    int* lrow = list + (size_t)b * L_;
    for (int j = 0; j < lc; ++j) lrow[excl + j] = loc[j];
    if (t == 0) {
      cnt[b] = total;
      endv[b] = L_ - total;
    }
    __syncthreads();

    // ---- pass 2: mlm>0 markers ----
    int mloc[8];
    int mc = 0;
#pragma unroll
    for (int j = 0; j < 8; ++j) {
      int l = base + j;
      if (mrow[l] > 0) mloc[mc++] = l;
    }
    int incl2 = mc;
#pragma unroll
    for (int o = 1; o < 64; o <<= 1) {
      int v = __shfl_up(incl2, o, 64);
      if (lane >= o) incl2 += v;
    }
    if (lane == 63) wsh[w] = incl2;
    __syncthreads();
    int pre2 = 0;
#pragma unroll
    for (int i = 0; i < 4; ++i) {
      if (i < w) pre2 += wsh[i];
    }
    int excl2 = pre2 + incl2 - mc;
    for (int j = 0; j < mc; ++j) {
      int idx = excl2 + j;
      if (idx < C_) starts[b * C_ + idx] = mloc[j];
    }
  } else if (bid == B_) {
    // ---- scalars ----
    float s = 0.f, s2 = 0.f;
    for (int i = t; i < A_; i += 256) {
      float q = query[i];
      s += q;
      s2 = fmaf(q, q, s2);
    }
    sf1[t] = s;
    sf2[t] = s2;
    __syncthreads();
    for (int off = 128; off >= 1; off >>= 1) {
      if (t < off) {
        sf1[t] += sf1[t + off];
        sf2[t] += sf2[t + off];
      }
      __syncthreads();
    }
    float qsum = sf1[0], qsq = sf2[0];
    __syncthreads();
    float wv = 0.f;
    for (int i = t; i < H_; i += 256) wv += Wcls[i];
    sf1[t] = wv;
    __syncthreads();
    for (int off = 128; off >= 1; off >>= 1) {
      if (t < off) sf1[t] += sf1[t + off];
      __syncthreads();
    }
    if (t == 0) {
      float var = (qsq - qsum * qsum / (float)A_) / (float)(A_ - 1);
      ws_scal[0] = sqrtf((float)A_ * var);
      ws_scal[1] = sf1[0];
    }
  } else {
    // ---- Wfrag conversion: block = (a_blk, kb-quarter) ----
    const int g4 = bid - B_ - 1;         // [0, 256)
    const int ga = g4 >> 2;              // a_blk in [0,64)
    const int q = g4 & 3;                // kb quarter
    const int row = ga * 16 + (lane & 15);
    const int colb = (lane >> 4) * 8;
    const float* srcrow = Wh + (size_t)row * H_;
#pragma unroll
    for (int i = 0; i < 2; ++i) {
      const int kb = q * 8 + w * 2 + i;
      const float* src = srcrow + kb * 32 + colb;
      float4 u0 = *(const float4*)src;
      float4 u1 = *(const float4*)(src + 4);
      union { short8v v; unsigned short h[8]; } o;
      o.h[0] = f2bf(u0.x); o.h[1] = f2bf(u0.y); o.h[2] = f2bf(u0.z); o.h[3] = f2bf(u0.w);
      o.h[4] = f2bf(u1.x); o.h[5] = f2bf(u1.y); o.h[6] = f2bf(u1.z); o.h[7] = f2bf(u1.w);
      *(short8v*)(Wfrag + (((size_t)ga * 32 + kb) * 64 + lane) * 8) = o.v;
    }
  }
}

// ============ kernel 2: kSP — probe (first) ∥ streaming W_cls dots ============
__global__ __launch_bounds__(256) void kSP(const float* __restrict__ inp,
                                           const unsigned short* __restrict__ Wfrag,
                                           const float* __restrict__ bh,
                                           const float* __restrict__ query,
                                           const float* __restrict__ Wcls,
                                           const int* __restrict__ attn,
                                           const int* __restrict__ cnt,
                                           const int* __restrict__ list,
                                           float* __restrict__ probe,
                                           float* __restrict__ d) {
  __shared__ __align__(16) unsigned short Xs[16][KPH + 8];  // 8.4 KB
  __shared__ float red[4][16];
  const int bid = blockIdx.x;
  const int t = threadIdx.x;
  const int w = t >> 6;
  const int lane = t & 63;

  if (bid >= PB_BLOCKS) {
    // ---- streaming part: 4 rows per wave ----
    const int r0 = (bid - PB_BLOCKS) * 16 + w * 4;
    const int a0v = attn[r0], a1v = attn[r0 + 1], a2v = attn[r0 + 2], a3v = attn[r0 + 3];
    if ((a0v | a1v | a2v | a3v) == 0) return;
    float4 wv4[4];
#pragma unroll
    for (int k = 0; k < 4; ++k) wv4[k] = *(const float4*)(Wcls + k * 256 + lane * 4);
    const float* p0 = inp + (size_t)r0 * H_;
    float4 x0[4], x1[4], x2[4], x3[4];
    if (a0v) {
#pragma unroll
      for (int k = 0; k < 4; ++k) x0[k] = *(const float4*)(p0 + k * 256 + lane * 4);
    }
    if (a1v) {
#pragma unroll
      for (int k = 0; k < 4; ++k) x1[k] = *(const float4*)(p0 + H_ + k * 256 + lane * 4);
    }
    if (a2v) {
#pragma unroll
      for (int k = 0; k < 4; ++k) x2[k] = *(const float4*)(p0 + 2 * H_ + k * 256 + lane * 4);
    }
    if (a3v) {
#pragma unroll
      for (int k = 0; k < 4; ++k) x3[k] = *(const float4*)(p0 + 3 * H_ + k * 256 + lane * 4);
    }
#define DOTROW(XV, AV, IDX)                                                          \
    if (AV) {                                                                        \
      float acc = 0.f;                                                               \
      _Pragma("unroll")                                                              \
      for (int k = 0; k < 4; ++k)                                                    \
        acc += XV[k].x * wv4[k].x + XV[k].y * wv4[k].y +                             \
               XV[k].z * wv4[k].z + XV[k].w * wv4[k].w;                              \
      _Pragma("unroll")                                                              \
      for (int o = 1; o < 64; o <<= 1) acc += __shfl_xor(acc, o, 64);                \
      if (lane == 0) d[r0 + IDX] = acc;                                              \
    }
    DOTROW(x0, a0v, 0)
    DOTROW(x1, a1v, 1)
    DOTROW(x2, a2v, 2)
    DOTROW(x3, a3v, 3)
#undef DOTROW
    return;
  }

  // ---- probe part (coalesced Wfrag reads) ----
  const int b = bid >> 3;
  const int sl = bid & 7;
  const int c0 = cnt[b];
  const int lg = lane >> 4;
  const int lc = lane & 15;

  const int srow = t >> 4;
  const int scol = (t & 15) * 16;
  int pi = srow;
  if (pi >= c0) pi = (c0 > 0) ? (c0 - 1) : 0;
  const int xl = (c0 > 0) ? list[(size_t)b * L_ + pi] : 0;
  const float* xptr = inp + ((size_t)(b * L_ + xl)) * H_ + scol;

  const unsigned short* wf = Wfrag + ((size_t)(sl * 8 + w * 2) * 32) * 512 + lane * 8;

  float4v acc0 = (float4v){0.f, 0.f, 0.f, 0.f};
  float4v acc1 = (float4v){0.f, 0.f, 0.f, 0.f};

  for (int ph = 0; ph < H_ / KPH; ++ph) {
    __syncthreads();
#pragma unroll
    for (int j = 0; j < 2; ++j) {
      float4 u0 = *(const float4*)(xptr + ph * KPH + j * 8);
      float4 u1 = *(const float4*)(xptr + ph * KPH + j * 8 + 4);
      union { short8v v; unsigned short h[8]; } o;
      o.h[0] = f2bf(u0.x); o.h[1] = f2bf(u0.y); o.h[2] = f2bf(u0.z); o.h[3] = f2bf(u0.w);
      o.h[4] = f2bf(u1.x); o.h[5] = f2bf(u1.y); o.h[6] = f2bf(u1.z); o.h[7] = f2bf(u1.w);
      *(short8v*)&Xs[srow][scol + j * 8] = o.v;
    }
    __syncthreads();
#pragma unroll
    for (int kk = 0; kk < 8; ++kk) {
      const int kb = ph * 8 + kk;
      short8v bv0 = *(const short8v*)(wf + (size_t)kb * 512);
      short8v bv1 = *(const short8v*)(wf + (size_t)kb * 512 + 32 * 512);
      short8v av = *(const short8v*)&Xs[lc][kk * 32 + lg * 8];
      acc0 = __builtin_amdgcn_mfma_f32_16x16x32_bf16(av, bv0, acc0, 0, 0, 0);
      acc1 = __builtin_amdgcn_mfma_f32_16x16x32_bf16(av, bv1, acc1, 0, 0, 0);
    }
  }

  float pp[4] = {0.f, 0.f, 0.f, 0.f};
  {
    const int ag0 = sl * 128 + w * 32 + lc;
    const float q0 = query[ag0];
    const float b0 = bh[ag0];
    const int ag1 = ag0 + 16;
    const float q1 = query[ag1];
    const float b1 = bh[ag1];
#pragma unroll
    for (int r = 0; r < 4; ++r) {
      pp[r] = fmaf(tanhf(acc0[r] + b0), q0, pp[r]);
      pp[r] = fmaf(tanhf(acc1[r] + b1), q1, pp[r]);
    }
  }
#pragma unroll
  for (int r = 0; r < 4; ++r) {
#pragma unroll
    for (int o = 1; o < 16; o <<= 1)
      pp[r] += __shfl_xor(pp[r], o, 64);
  }
  __syncthreads();
  if (lc == 0) {
#pragma unroll
    for (int r = 0; r < 4; ++r) red[w][lg * 4 + r] = pp[r];
  }
  __syncthreads();
  if (t < 16) {
    float s = red[0][t] + red[1][t] + red[2][t] + red[3][t];
    probe[((size_t)b * PBS + sl) * 16 + t] = (c0 > 0) ? s : 0.f;
  }
}

// ============ kernel 3: kTail — cert + (self-contained fallback) + outputs ============
// One block per batch. Certified (normal): att0 = 0, only segment sums run.
// Uncertified (never observed): block recomputes ALL masked logits itself via the
// same Wfrag MFMA pipeline — slow but correct, no cross-kernel ordering needed.
__global__ __launch_bounds__(256) void kTail(const int* __restrict__ cnt,
                                             const int* __restrict__ list,
                                             const float* __restrict__ ws_scal,
                                             const float* __restrict__ d,
                                             const int* __restrict__ starts,
                                             const int* __restrict__ endv,
                                             const float* __restrict__ probe,
                                             const unsigned short* __restrict__ Wfrag,
                                             const float* __restrict__ inp,
                                             const float* __restrict__ bh,
                                             const float* __restrict__ query,
                                             const float* __restrict__ bcls,
                                             float* __restrict__ out) {
  __shared__ float lgs[L_];
  __shared__ float sred[256];
  __shared__ __align__(16) unsigned short Xs[16][KPH + 8];
  __shared__ float red[4][16];
  __shared__ int sskip;
  const int b = blockIdx.x;
  const int t = threadIdx.x;
  const int w = t >> 6;
  const int lane = t & 63;
  const float denom = ws_scal[0];
  const int c0 = cnt[b];

  if (t == 0) sskip = 0;
  __syncthreads();
  if (t < 16) {
    float s = 0.f;
#pragma unroll
    for (int p8 = 0; p8 < PBS; ++p8) s += probe[((size_t)b * PBS + p8) * 16 + t];
    float logit = -1000.0f * (s / denom);
    if (logit >= PROBE_THRESH) atomicOr(&sskip, 1);
  }
  __syncthreads();
  const bool skip = (c0 > 0) && (sskip != 0);

  float att0 = 0.0f;
  if (!skip) {
    const int lgp = lane >> 4;
    const int lc = lane & 15;
    const int srow = t >> 4;
    const int scol = (t & 15) * 16;
    const int ntile = (c0 + 15) >> 4;
    for (int tile = 0; tile < ntile; ++tile) {
      int pi = tile * 16 + srow;
      if (pi >= c0) pi = c0 - 1;
      const int xl = list[(size_t)b * L_ + pi];
      const float* xptr = inp + ((size_t)(b * L_ + xl)) * H_ + scol;
      float4v acc[8][2];
#pragma unroll
      for (int sl = 0; sl < 8; ++sl) {
        acc[sl][0] = (float4v){0.f, 0.f, 0.f, 0.f};
        acc[sl][1] = (float4v){0.f, 0.f, 0.f, 0.f};
      }
      for (int ph = 0; ph < H_ / KPH; ++ph) {
        __syncthreads();
#pragma unroll
        for (int j = 0; j < 2; ++j) {
          float4 u0 = *(const float4*)(xptr + ph * KPH + j * 8);
          float4 u1 = *(const float4*)(xptr + ph * KPH + j * 8 + 4);
          union { short8v v; unsigned short h[8]; } o;
          o.h[0] = f2bf(u0.x); o.h[1] = f2bf(u0.y); o.h[2] = f2bf(u0.z); o.h[3] = f2bf(u0.w);
          o.h[4] = f2bf(u1.x); o.h[5] = f2bf(u1.y); o.h[6] = f2bf(u1.z); o.h[7] = f2bf(u1.w);
          *(short8v*)&Xs[srow][scol + j * 8] = o.v;
        }
        __syncthreads();
#pragma unroll
        for (int sl = 0; sl < 8; ++sl) {
          const unsigned short* wf = Wfrag + ((size_t)(sl * 8 + w * 2) * 32) * 512 + lane * 8;
#pragma unroll
          for (int kk = 0; kk < 8; ++kk) {
            const int kb = ph * 8 + kk;
            short8v bv0 = *(const short8v*)(wf + (size_t)kb * 512);
            short8v bv1 = *(const short8v*)(wf + (size_t)kb * 512 + 32 * 512);
            short8v av = *(const short8v*)&Xs[lc][kk * 32 + lgp * 8];
            acc[sl][0] = __builtin_amdgcn_mfma_f32_16x16x32_bf16(av, bv0, acc[sl][0], 0, 0, 0);
            acc[sl][1] = __builtin_amdgcn_mfma_f32_16x16x32_bf16(av, bv1, acc[sl][1], 0, 0, 0);
          }
        }
      }
      float pp[4] = {0.f, 0.f, 0.f, 0.f};
#pragma unroll
      for (int sl = 0; sl < 8; ++sl) {
        const int ag0 = sl * 128 + w * 32 + lc;
        const float q0 = query[ag0];
        const float b0 = bh[ag0];
        const int ag1 = ag0 + 16;
        const float q1 = query[ag1];
        const float b1 = bh[ag1];
#pragma unroll
        for (int r = 0; r < 4; ++r) {
          pp[r] = fmaf(tanhf(acc[sl][0][r] + b0), q0, pp[r]);
          pp[r] = fmaf(tanhf(acc[sl][1][r] + b1), q1, pp[r]);
        }
      }
#pragma unroll
      for (int r = 0; r < 4; ++r) {
#pragma unroll
        for (int o = 1; o < 16; o <<= 1)
          pp[r] += __shfl_xor(pp[r], o, 64);
      }
      __syncthreads();
      if (lc == 0) {
#pragma unroll
        for (int r = 0; r < 4; ++r) red[w][lgp * 4 + r] = pp[r];
      }
      __syncthreads();
      if (t < 16) {
        const int row = tile * 16 + t;
        if (row < c0) {
          float s = red[0][t] + red[1][t] + red[2][t] + red[3][t];
          lgs[row] = -1000.0f * (s / denom);
        }
      }
      __syncthreads();
    }

    // m, Z over masked logits + attended zeros
    float mx = 0.0f;
    for (int i = t; i < c0; i += 256) mx = fmaxf(mx, lgs[i]);
    sred[t] = mx;
    __syncthreads();
    for (int off = 128; off >= 1; off >>= 1) {
      if (t < off) sred[t] = fmaxf(sred[t], sred[t + off]);
      __syncthreads();
    }
    const float m = sred[0];
    __syncthreads();
    float zs = 0.f;
    for (int i = t; i < c0; i += 256) zs += expf(lgs[i] - m);
    if (t == 0) zs += (float)(L_ - c0) * expf(-m);
    sred[t] = zs;
    __syncthreads();
    for (int off = 128; off >= 1; off >>= 1) {
      if (t < off) sred[t] += sred[t + off];
      __syncthreads();
    }
    const float Z = sred[0];
    __syncthreads();
    att0 = expf(-m) / Z;
  }

  // segment sums + outputs
  for (int c = 0; c < C_; ++c) {
    const int st = starts[b * C_ + c];
    const int bound = (c < C_ - 1) ? (starts[b * C_ + c + 1] - 1) : (endv[b] - 1);
    const int lo = st + 1;
    const int hi = bound;
    float a = 0.f;
    for (int l = lo + t; l < hi; l += 256) a += d[(size_t)b * L_ + l];
    sred[t] = a;
    __syncthreads();
    for (int off = 128; off >= 1; off >>= 1) {
      if (t < off) sred[t] += sred[t + off];
      __syncthreads();
    }
    if (t == 0) {
      int count = hi - lo;
      if (count < 0) count = 0;
      out[b * C_ + c] = sred[0] + ws_scal[1] * att0 * (float)count + bcls[0];
    }
    __syncthreads();
  }
}

extern "C" void kernel_launch(void* const* d_in, const int* in_sizes, int n_in,
                              void* d_out, int out_size, void* d_ws, size_t ws_size,
                              hipStream_t stream) {
  const float* inp   = (const float*)d_in[0];
  const int*   attn  = (const int*)d_in[1];
  const int*   mlm   = (const int*)d_in[2];
  const float* Wh    = (const float*)d_in[3];
  const float* bh    = (const float*)d_in[4];
  const float* query = (const float*)d_in[5];
  const float* Wcls  = (const float*)d_in[6];
  const float* bcls  = (const float*)d_in[7];
  float* out = (float*)d_out;

  char* ws = (char*)d_ws;
  float*          ws_scal = (float*)(ws + OFF_SCAL);
  int*            endv    = (int*)(ws + OFF_END);
  int*            cnt     = (int*)(ws + OFF_CNT);
  int*            starts  = (int*)(ws + OFF_STARTS);
  int*            list    = (int*)(ws + OFF_LIST);
  unsigned short* Wfrag   = (unsigned short*)(ws + OFF_WF);
  float*          dvec    = (float*)(ws + OFF_D);
  float*          probe   = (float*)(ws + OFF_PROBE);

  hipLaunchKernelGGL(kPrep, dim3(B_ + 1 + KW_BLOCKS), dim3(256), 0, stream,
                     attn, mlm, query, Wcls, Wh, ws_scal, endv, cnt, starts, list, Wfrag);
  hipLaunchKernelGGL(kSP, dim3(PB_BLOCKS + KE_BLOCKS), dim3(256), 0, stream,
                     inp, Wfrag, bh, query, Wcls, attn, cnt, list, probe, dvec);
  hipLaunchKernelGGL(kTail, dim3(B_), dim3(256), 0, stream,
                     cnt, list, ws_scal, dvec, starts, endv, probe, Wfrag, inp, bh,
                     query, bcls, out);
}